// Round 1
// baseline (426.516 us; speedup 1.0000x reference)
//
#include <hip/hip_runtime.h>
#include <math.h>

// Problem constants
#define CCH 64
#define HH  128
#define WW  128
#define EHW 64
#define NB  4
#define NPIX (NB*HH*WW)   // 65536

// ---------------------------------------------------------------------------
// Prep: transpose conv weights so inner output-channel loops read contiguous
// wave-uniform rows (-> s_load_dwordx16).
//   offT[(ic*9+kk)*32 + o]  = off_w[o*576 + ic*9 + kk]   (o<27, padded to 32)
//   dcnT[(k*64+ic)*64 + o]  = dcn_w[o*576 + ic*9 + k]
// ---------------------------------------------------------------------------
__global__ __launch_bounds__(256) void prep_kernel(
    const float* __restrict__ off_w, const float* __restrict__ dcn_w,
    float* __restrict__ offT, float* __restrict__ dcnT)
{
    int idx = blockIdx.x * 256 + threadIdx.x;
    if (idx < 576 * 27) {
        int rc = idx / 27;       // ic*9+kk
        int o  = idx % 27;
        offT[rc * 32 + o] = off_w[o * 576 + rc];
    }
    if (idx < 36864) {
        int o    = idx & 63;
        int rest = idx >> 6;
        int ic   = rest & 63;
        int k    = rest >> 6;
        dcnT[(k * 64 + ic) * 64 + o] = dcn_w[o * 576 + ic * 9 + k];
    }
}

// ---------------------------------------------------------------------------
// Kernel 1: fused 4-layer MLP -> feat (NCHW).
// thread = pixel; weights wave-uniform (SGPR); activations in a private LDS
// column (runtime-indexable without scratch; lanes consecutive -> no bank
// conflicts, no barriers since each thread touches only its own column).
// ---------------------------------------------------------------------------
__device__ __forceinline__ void mlp_layer(const float* __restrict__ W,
                                          const float* __restrict__ Bv,
                                          float* xcol)
{
    float acc[64];
#pragma unroll
    for (int c = 0; c < 64; ++c) acc[c] = Bv[c];
    for (int i = 0; i < 64; ++i) {
        float v = xcol[i * 256];
        const float* wr = W + i * 64;
#pragma unroll
        for (int c = 0; c < 64; ++c) acc[c] = fmaf(v, wr[c], acc[c]);
    }
#pragma unroll
    for (int c = 0; c < 64; ++c) xcol[c * 256] = fmaxf(acc[c], 0.0f);
}

__global__ __launch_bounds__(256) void mlp_kernel(
    const float* __restrict__ ev, const float* __restrict__ im,
    const float* __restrict__ w0, const float* __restrict__ b0,
    const float* __restrict__ w1, const float* __restrict__ b1,
    const float* __restrict__ w2, const float* __restrict__ b2,
    const float* __restrict__ w3, const float* __restrict__ b3,
    float* __restrict__ feat)
{
    __shared__ float xbuf[64 * 256];   // 64 KiB: [i][tid] layout
    int tid = threadIdx.x;
    int p = blockIdx.x * 256 + tid;
    int b = p >> 14;
    int q = p & 16383;
    int h = q >> 7;
    int w = q & 127;
    float* xcol = &xbuf[tid];

    float acc[64];
#pragma unroll
    for (int c = 0; c < 64; ++c) acc[c] = b0[c];

    // inputs 0..63: ev_feat at (h>>1, w>>1)
    const float* evb = ev + ((b * 64) * 64 + (h >> 1)) * 64 + (w >> 1);
    for (int i = 0; i < 64; ++i) {
        float v = evb[i * 4096];
        const float* wr = w0 + i * 64;
#pragma unroll
        for (int c = 0; c < 64; ++c) acc[c] = fmaf(v, wr[c], acc[c]);
    }
    // inputs 64..127: im_feat at (h, w)
    const float* imb = im + ((b * 64) * 128 + h) * 128 + w;
    for (int i = 0; i < 64; ++i) {
        float v = imb[i * 16384];
        const float* wr = w0 + (64 + i) * 64;
#pragma unroll
        for (int c = 0; c < 64; ++c) acc[c] = fmaf(v, wr[c], acc[c]);
    }
    // inputs 128..131: rel_y, rel_x, 1, 1
    {
        float rely = (h & 1) ? 0.5f : -0.5f;
        float relx = (w & 1) ? 0.5f : -0.5f;
        const float* wr = w0 + 128 * 64;
#pragma unroll
        for (int c = 0; c < 64; ++c) acc[c] = fmaf(rely, wr[c], acc[c]);
#pragma unroll
        for (int c = 0; c < 64; ++c) acc[c] = fmaf(relx, wr[64 + c], acc[c]);
#pragma unroll
        for (int c = 0; c < 64; ++c) acc[c] += wr[128 + c] + wr[192 + c];
    }
#pragma unroll
    for (int c = 0; c < 64; ++c) xcol[c * 256] = fmaxf(acc[c], 0.0f);

    mlp_layer(w1, b1, xcol);
    mlp_layer(w2, b2, xcol);

    // layer 3 (no relu) -> feat
#pragma unroll
    for (int c = 0; c < 64; ++c) acc[c] = b3[c];
    for (int i = 0; i < 64; ++i) {
        float v = xcol[i * 256];
        const float* wr = w3 + i * 64;
#pragma unroll
        for (int c = 0; c < 64; ++c) acc[c] = fmaf(v, wr[c], acc[c]);
    }
    float* fb = feat + (b * 64) * 16384 + q;
#pragma unroll
    for (int c = 0; c < 64; ++c) fb[c * 16384] = acc[c];
}

// ---------------------------------------------------------------------------
// Kernel 2: 3x3 offset conv (27 ch) + transform to py/px/mask.
// ---------------------------------------------------------------------------
__global__ __launch_bounds__(256) void off_kernel(
    const float* __restrict__ feat, const float* __restrict__ offT,
    const float* __restrict__ off_b,
    float* __restrict__ py_, float* __restrict__ px_, float* __restrict__ mask_)
{
    int p = blockIdx.x * 256 + threadIdx.x;
    int b = p >> 14;
    int q = p & 16383;
    int h = q >> 7;
    int w = q & 127;

    float acc[27];
#pragma unroll
    for (int o = 0; o < 27; ++o) acc[o] = off_b[o];

    const float* fb = feat + (b * 64) * 16384;
    for (int ic = 0; ic < 64; ++ic) {
        const float* f = fb + ic * 16384;
        float v[9];
#pragma unroll
        for (int ky = 0; ky < 3; ++ky)
#pragma unroll
            for (int kx = 0; kx < 3; ++kx) {
                int y = h + ky - 1, x = w + kx - 1;
                bool ok = (y >= 0) && (y < 128) && (x >= 0) && (x < 128);
                v[ky * 3 + kx] = ok ? f[y * 128 + x] : 0.0f;
            }
#pragma unroll
        for (int kk = 0; kk < 9; ++kk) {
            const float* wr = offT + (ic * 9 + kk) * 32;
#pragma unroll
            for (int o = 0; o < 27; ++o) acc[o] = fmaf(v[kk], wr[o], acc[o]);
        }
    }

#pragma unroll
    for (int k = 0; k < 9; ++k) {
        float oy = acc[2 * k];
        float ox = acc[2 * k + 1];
        float mm = 1.0f / (1.0f + expf(-acc[18 + k]));
        int idx = ((b * 9 + k) << 14) + q;
        py_[idx]   = (float)(h + k / 3 - 1) + oy;
        px_[idx]   = (float)(w + k % 3 - 1) + ox;
        mask_[idx] = mm;
    }
}

// ---------------------------------------------------------------------------
// Kernel 3: deformable sampling + 64x64x9 einsum + bias.
// ---------------------------------------------------------------------------
__global__ __launch_bounds__(256) void dcn_kernel(
    const float* __restrict__ feat,
    const float* __restrict__ py_, const float* __restrict__ px_,
    const float* __restrict__ mask_,
    const float* __restrict__ dcnT, const float* __restrict__ dcn_b,
    float* __restrict__ out)
{
    int p = blockIdx.x * 256 + threadIdx.x;
    int b = p >> 14;
    int q = p & 16383;

    float acc[64];
#pragma unroll
    for (int o = 0; o < 64; ++o) acc[o] = dcn_b[o];

    const float* fb = feat + (b * 64) * 16384;
    for (int k = 0; k < 9; ++k) {
        int idx = ((b * 9 + k) << 14) + q;
        float py = py_[idx];
        float px = px_[idx];
        float m  = mask_[idx];

        float y0f = floorf(py), x0f = floorf(px);
        float ly = py - y0f, lx = px - x0f;
        int y0 = (int)y0f, x0 = (int)x0f;

        bool vy0 = (y0f >= 0.0f)        && (y0f <= 127.0f);
        bool vy1 = (y0f + 1.0f >= 0.0f) && (y0f + 1.0f <= 127.0f);
        bool vx0 = (x0f >= 0.0f)        && (x0f <= 127.0f);
        bool vx1 = (x0f + 1.0f >= 0.0f) && (x0f + 1.0f <= 127.0f);

        int yc0 = min(max(y0, 0), 127),     yc1 = min(max(y0 + 1, 0), 127);
        int xc0 = min(max(x0, 0), 127),     xc1 = min(max(x0 + 1, 0), 127);

        float w00 = (1.0f - ly) * (1.0f - lx) * m * ((vy0 && vx0) ? 1.0f : 0.0f);
        float w01 = (1.0f - ly) * lx          * m * ((vy0 && vx1) ? 1.0f : 0.0f);
        float w10 = ly * (1.0f - lx)          * m * ((vy1 && vx0) ? 1.0f : 0.0f);
        float w11 = ly * lx                   * m * ((vy1 && vx1) ? 1.0f : 0.0f);

        int i00 = yc0 * 128 + xc0, i01 = yc0 * 128 + xc1;
        int i10 = yc1 * 128 + xc0, i11 = yc1 * 128 + xc1;

        const float* dT = dcnT + (k * 64) * 64;
        for (int ic = 0; ic < 64; ++ic) {
            const float* f = fb + ic * 16384;
            float s = w00 * f[i00] + w01 * f[i01] + w10 * f[i10] + w11 * f[i11];
            const float* wr = dT + ic * 64;
#pragma unroll
            for (int o = 0; o < 64; ++o) acc[o] = fmaf(s, wr[o], acc[o]);
        }
    }

    float* ob = out + (b * 64) * 16384 + q;
#pragma unroll
    for (int o = 0; o < 64; ++o) ob[o * 16384] = acc[o];
}

// ---------------------------------------------------------------------------
extern "C" void kernel_launch(void* const* d_in, const int* in_sizes, int n_in,
                              void* d_out, int out_size, void* d_ws, size_t ws_size,
                              hipStream_t stream)
{
    const float* ev    = (const float*)d_in[0];
    const float* im    = (const float*)d_in[1];
    const float* w0    = (const float*)d_in[2];
    const float* b0    = (const float*)d_in[3];
    const float* w1    = (const float*)d_in[4];
    const float* b1    = (const float*)d_in[5];
    const float* w2    = (const float*)d_in[6];
    const float* b2    = (const float*)d_in[7];
    const float* w3    = (const float*)d_in[8];
    const float* b3    = (const float*)d_in[9];
    const float* off_w = (const float*)d_in[10];
    const float* off_b = (const float*)d_in[11];
    const float* dcn_w = (const float*)d_in[12];
    const float* dcn_b = (const float*)d_in[13];
    float* out = (float*)d_out;

    char* ws = (char*)d_ws;
    float* feat  = (float*)(ws);                       // 16,777,216 B
    float* py_   = (float*)(ws + 16777216);            //  2,359,296 B
    float* px_   = (float*)(ws + 19136512);            //  2,359,296 B
    float* mask_ = (float*)(ws + 21495808);            //  2,359,296 B
    float* offT  = (float*)(ws + 23855104);            //     73,728 B
    float* dcnT  = (float*)(ws + 23928832);            //    147,456 B

    prep_kernel<<<144, 256, 0, stream>>>(off_w, dcn_w, offT, dcnT);
    mlp_kernel<<<NPIX / 256, 256, 0, stream>>>(ev, im, w0, b0, w1, b1, w2, b2,
                                               w3, b3, feat);
    off_kernel<<<NPIX / 256, 256, 0, stream>>>(feat, offT, off_b, py_, px_, mask_);
    dcn_kernel<<<NPIX / 256, 256, 0, stream>>>(feat, py_, px_, mask_, dcnT,
                                               dcn_b, out);
}

// Round 2
// 423.069 us; speedup vs baseline: 1.0081x; 1.0081x over previous
//
#include <hip/hip_runtime.h>
#include <math.h>

// Problem constants
#define CCH 64
#define HH  128
#define WW  128
#define NB  4
#define NPIX (NB*HH*WW)   // 65536

// ---------------------------------------------------------------------------
// Prep: transpose conv weights for wave-uniform contiguous rows.
//   offT[(ic*9+kk)*28 + o]  = off_w[o*576 + ic*9 + kk]   (o<27, pad->0)
//   dcnT[(k*64+ic)*64 + o]  = dcn_w[o*576 + ic*9 + k]
// ---------------------------------------------------------------------------
__global__ __launch_bounds__(256) void prep_kernel(
    const float* __restrict__ off_w, const float* __restrict__ dcn_w,
    float* __restrict__ offT, float* __restrict__ dcnT)
{
    int idx = blockIdx.x * 256 + threadIdx.x;
    if (idx < 576 * 28) {
        int rc = idx / 28;       // ic*9+kk
        int o  = idx % 28;
        offT[rc * 28 + o] = (o < 27) ? off_w[o * 576 + rc] : 0.0f;
    }
    if (idx < 36864) {
        int o    = idx & 63;
        int rest = idx >> 6;
        int ic   = rest & 63;
        int k    = rest >> 6;
        dcnT[(k * 64 + ic) * 64 + o] = dcn_w[o * 576 + ic * 9 + k];
    }
}

// ---------------------------------------------------------------------------
// Kernel 1: fused 4-layer MLP -> feat (NCHW).
// Block = 64 pixels x 4 waves; wave cg computes channels [16cg,16cg+16).
// Activations exchanged via double-buffered LDS x[ch][pix] (conflict-free).
// ---------------------------------------------------------------------------
__global__ __launch_bounds__(256) void mlp_kernel(
    const float* __restrict__ ev, const float* __restrict__ im,
    const float* __restrict__ w0, const float* __restrict__ b0,
    const float* __restrict__ w1, const float* __restrict__ b1,
    const float* __restrict__ w2, const float* __restrict__ b2,
    const float* __restrict__ w3, const float* __restrict__ b3,
    float* __restrict__ feat)
{
    __shared__ float xA[64 * 64];   // [ch][pix]
    __shared__ float xB[64 * 64];
    int tid  = threadIdx.x;
    int cg   = __builtin_amdgcn_readfirstlane(tid >> 6);   // wave-uniform
    int lane = tid & 63;
    int p = blockIdx.x * 64 + lane;
    int b = p >> 14;
    int q = p & 16383;
    int h = q >> 7;
    int w = q & 127;
    int c0 = cg * 16;

    float acc[16];
#pragma unroll
    for (int j = 0; j < 16; ++j) acc[j] = b0[c0 + j];

    // inputs 0..63: ev_feat at (h>>1, w>>1)
    const float* evb = ev + ((b * 64) * 64 + (h >> 1)) * 64 + (w >> 1);
    for (int i = 0; i < 64; ++i) {
        float v = evb[i * 4096];
        const float* wr = w0 + i * 64 + c0;
#pragma unroll
        for (int j = 0; j < 16; ++j) acc[j] = fmaf(v, wr[j], acc[j]);
    }
    // inputs 64..127: im_feat at (h, w)
    const float* imb = im + ((b * 64) * 128 + h) * 128 + w;
    for (int i = 0; i < 64; ++i) {
        float v = imb[i * 16384];
        const float* wr = w0 + (64 + i) * 64 + c0;
#pragma unroll
        for (int j = 0; j < 16; ++j) acc[j] = fmaf(v, wr[j], acc[j]);
    }
    // inputs 128..131: rel_y, rel_x, 1, 1
    {
        float rely = (h & 1) ? 0.5f : -0.5f;
        float relx = (w & 1) ? 0.5f : -0.5f;
        const float* wr = w0 + 128 * 64 + c0;
#pragma unroll
        for (int j = 0; j < 16; ++j) acc[j] = fmaf(rely, wr[j], acc[j]);
#pragma unroll
        for (int j = 0; j < 16; ++j) acc[j] = fmaf(relx, wr[64 + j], acc[j]);
#pragma unroll
        for (int j = 0; j < 16; ++j) acc[j] += wr[128 + j] + wr[192 + j];
    }
#pragma unroll
    for (int j = 0; j < 16; ++j) xA[(c0 + j) * 64 + lane] = fmaxf(acc[j], 0.0f);
    __syncthreads();

    // layer 1: read xA -> write xB
#pragma unroll
    for (int j = 0; j < 16; ++j) acc[j] = b1[c0 + j];
    for (int i = 0; i < 64; ++i) {
        float v = xA[i * 64 + lane];
        const float* wr = w1 + i * 64 + c0;
#pragma unroll
        for (int j = 0; j < 16; ++j) acc[j] = fmaf(v, wr[j], acc[j]);
    }
#pragma unroll
    for (int j = 0; j < 16; ++j) xB[(c0 + j) * 64 + lane] = fmaxf(acc[j], 0.0f);
    __syncthreads();

    // layer 2: read xB -> write xA
#pragma unroll
    for (int j = 0; j < 16; ++j) acc[j] = b2[c0 + j];
    for (int i = 0; i < 64; ++i) {
        float v = xB[i * 64 + lane];
        const float* wr = w2 + i * 64 + c0;
#pragma unroll
        for (int j = 0; j < 16; ++j) acc[j] = fmaf(v, wr[j], acc[j]);
    }
#pragma unroll
    for (int j = 0; j < 16; ++j) xA[(c0 + j) * 64 + lane] = fmaxf(acc[j], 0.0f);
    __syncthreads();

    // layer 3 (no relu): read xA -> feat
#pragma unroll
    for (int j = 0; j < 16; ++j) acc[j] = b3[c0 + j];
    for (int i = 0; i < 64; ++i) {
        float v = xA[i * 64 + lane];
        const float* wr = w3 + i * 64 + c0;
#pragma unroll
        for (int j = 0; j < 16; ++j) acc[j] = fmaf(v, wr[j], acc[j]);
    }
    float* fb = feat + (b * 64 + c0) * 16384 + q;
#pragma unroll
    for (int j = 0; j < 16; ++j) fb[j * 16384] = acc[j];
}

// ---------------------------------------------------------------------------
// Kernel 2: 3x3 offset conv -> raw 27-channel output oo (transform deferred).
// Block = 64 pixels x 4 waves; wave og computes outputs [7og, 7og+7) (<27).
// ---------------------------------------------------------------------------
__global__ __launch_bounds__(256) void off_kernel(
    const float* __restrict__ feat, const float* __restrict__ offT,
    const float* __restrict__ off_b,
    float* __restrict__ oo)
{
    int tid  = threadIdx.x;
    int og   = __builtin_amdgcn_readfirstlane(tid >> 6);
    int lane = tid & 63;
    int p = blockIdx.x * 64 + lane;
    int b = p >> 14;
    int q = p & 16383;
    int h = q >> 7;
    int w = q & 127;
    int o0 = og * 7;

    float acc[7];
#pragma unroll
    for (int j = 0; j < 7; ++j) acc[j] = (o0 + j < 27) ? off_b[o0 + j] : 0.0f;

    const float* fb = feat + (b * 64) * 16384;
    for (int ic = 0; ic < 64; ++ic) {
        const float* f = fb + ic * 16384;
        float v[9];
#pragma unroll
        for (int ky = 0; ky < 3; ++ky)
#pragma unroll
            for (int kx = 0; kx < 3; ++kx) {
                int y = h + ky - 1, x = w + kx - 1;
                bool ok = (y >= 0) && (y < 128) && (x >= 0) && (x < 128);
                v[ky * 3 + kx] = ok ? f[y * 128 + x] : 0.0f;
            }
#pragma unroll
        for (int kk = 0; kk < 9; ++kk) {
            const float* wr = offT + (ic * 9 + kk) * 28 + o0;
#pragma unroll
            for (int j = 0; j < 7; ++j) acc[j] = fmaf(v[kk], wr[j], acc[j]);
        }
    }

#pragma unroll
    for (int j = 0; j < 7; ++j) {
        int o = o0 + j;
        if (o < 27) oo[((b * 27 + o) << 14) + q] = acc[j];
    }
}

// ---------------------------------------------------------------------------
// Kernel 3: offset transform + deformable sampling + einsum + bias.
// Block = 64 pixels x 4 waves; wave og computes outputs [16og, 16og+16).
// ---------------------------------------------------------------------------
__global__ __launch_bounds__(256) void dcn_kernel(
    const float* __restrict__ feat,
    const float* __restrict__ oo,
    const float* __restrict__ dcnT, const float* __restrict__ dcn_b,
    float* __restrict__ out)
{
    int tid  = threadIdx.x;
    int og   = __builtin_amdgcn_readfirstlane(tid >> 6);
    int lane = tid & 63;
    int p = blockIdx.x * 64 + lane;
    int b = p >> 14;
    int q = p & 16383;
    int h = q >> 7;
    int w = q & 127;
    int o0 = og * 16;

    float acc[16];
#pragma unroll
    for (int j = 0; j < 16; ++j) acc[j] = dcn_b[o0 + j];

    const float* fb  = feat + (b * 64) * 16384;
    const float* oob = oo + ((b * 27) << 14) + q;

    for (int k = 0; k < 9; ++k) {
        float oy = oob[(2 * k) << 14];
        float ox = oob[(2 * k + 1) << 14];
        float ml = 1.0f / (1.0f + expf(-oob[(18 + k) << 14]));
        float py = (float)(h + k / 3 - 1) + oy;
        float px = (float)(w + k % 3 - 1) + ox;

        float y0f = floorf(py), x0f = floorf(px);
        float ly = py - y0f, lx = px - x0f;
        int y0 = (int)y0f, x0 = (int)x0f;

        bool vy0 = (y0f >= 0.0f)        && (y0f <= 127.0f);
        bool vy1 = (y0f + 1.0f >= 0.0f) && (y0f + 1.0f <= 127.0f);
        bool vx0 = (x0f >= 0.0f)        && (x0f <= 127.0f);
        bool vx1 = (x0f + 1.0f >= 0.0f) && (x0f + 1.0f <= 127.0f);

        int yc0 = min(max(y0, 0), 127),     yc1 = min(max(y0 + 1, 0), 127);
        int xc0 = min(max(x0, 0), 127),     xc1 = min(max(x0 + 1, 0), 127);

        float w00 = (1.0f - ly) * (1.0f - lx) * ml * ((vy0 && vx0) ? 1.0f : 0.0f);
        float w01 = (1.0f - ly) * lx          * ml * ((vy0 && vx1) ? 1.0f : 0.0f);
        float w10 = ly * (1.0f - lx)          * ml * ((vy1 && vx0) ? 1.0f : 0.0f);
        float w11 = ly * lx                   * ml * ((vy1 && vx1) ? 1.0f : 0.0f);

        int i00 = yc0 * 128 + xc0, i01 = yc0 * 128 + xc1;
        int i10 = yc1 * 128 + xc0, i11 = yc1 * 128 + xc1;

        const float* dT = dcnT + (k * 64) * 64 + o0;
        for (int ic = 0; ic < 64; ++ic) {
            const float* f = fb + ic * 16384;
            float s = w00 * f[i00] + w01 * f[i01] + w10 * f[i10] + w11 * f[i11];
            const float* wr = dT + ic * 64;
#pragma unroll
            for (int j = 0; j < 16; ++j) acc[j] = fmaf(s, wr[j], acc[j]);
        }
    }

    float* ob = out + (b * 64 + o0) * 16384 + q;
#pragma unroll
    for (int j = 0; j < 16; ++j) ob[j * 16384] = acc[j];
}

// ---------------------------------------------------------------------------
extern "C" void kernel_launch(void* const* d_in, const int* in_sizes, int n_in,
                              void* d_out, int out_size, void* d_ws, size_t ws_size,
                              hipStream_t stream)
{
    const float* ev    = (const float*)d_in[0];
    const float* im    = (const float*)d_in[1];
    const float* w0    = (const float*)d_in[2];
    const float* b0    = (const float*)d_in[3];
    const float* w1    = (const float*)d_in[4];
    const float* b1    = (const float*)d_in[5];
    const float* w2    = (const float*)d_in[6];
    const float* b2    = (const float*)d_in[7];
    const float* w3    = (const float*)d_in[8];
    const float* b3    = (const float*)d_in[9];
    const float* off_w = (const float*)d_in[10];
    const float* off_b = (const float*)d_in[11];
    const float* dcn_w = (const float*)d_in[12];
    const float* dcn_b = (const float*)d_in[13];
    float* out = (float*)d_out;

    char* ws = (char*)d_ws;
    float* feat  = (float*)(ws);                       // 16,777,216 B
    float* oo    = (float*)(ws + 16777216);            //  7,077,888 B
    float* offT  = (float*)(ws + 23855104);            //     64,512 B
    float* dcnT  = (float*)(ws + 23920640);            //    147,456 B

    prep_kernel<<<144, 256, 0, stream>>>(off_w, dcn_w, offT, dcnT);
    mlp_kernel<<<NPIX / 64, 256, 0, stream>>>(ev, im, w0, b0, w1, b1, w2, b2,
                                              w3, b3, feat);
    off_kernel<<<NPIX / 64, 256, 0, stream>>>(feat, offT, off_b, oo);
    dcn_kernel<<<NPIX / 64, 256, 0, stream>>>(feat, oo, dcnT, dcn_b, out);
}

// Round 3
// 195.383 us; speedup vs baseline: 2.1830x; 2.1653x over previous
//
#include <hip/hip_runtime.h>
#include <math.h>

// Problem constants
#define CCH 64
#define HH  128
#define WW  128
#define NB  4
#define NPIX (NB*HH*WW)   // 65536

// ---------------------------------------------------------------------------
// Prep: transpose conv weights for wave-uniform contiguous rows.
//   offT[(ic*9+kk)*28 + o]  = off_w[o*576 + ic*9 + kk]   (o<27, pad->0)
//   dcnT[(k*64+ic)*64 + o]  = dcn_w[o*576 + ic*9 + k]
// ---------------------------------------------------------------------------
__global__ __launch_bounds__(256) void prep_kernel(
    const float* __restrict__ off_w, const float* __restrict__ dcn_w,
    float* __restrict__ offT, float* __restrict__ dcnT)
{
    int idx = blockIdx.x * 256 + threadIdx.x;
    if (idx < 576 * 28) {
        int rc = idx / 28;       // ic*9+kk
        int o  = idx % 28;
        offT[rc * 28 + o] = (o < 27) ? off_w[o * 576 + rc] : 0.0f;
    }
    if (idx < 36864) {
        int o    = idx & 63;
        int rest = idx >> 6;
        int ic   = rest & 63;
        int k    = rest >> 6;
        dcnT[(k * 64 + ic) * 64 + o] = dcn_w[o * 576 + ic * 9 + k];
    }
}

// ---------------------------------------------------------------------------
// Kernel 1: fused 4-layer MLP -> feat (NCHW).
// Block = 64 pixels x 4 waves; wave cg computes channels [16cg,16cg+16).
// ---------------------------------------------------------------------------
__global__ __launch_bounds__(256) void mlp_kernel(
    const float* __restrict__ ev, const float* __restrict__ im,
    const float* __restrict__ w0, const float* __restrict__ b0,
    const float* __restrict__ w1, const float* __restrict__ b1,
    const float* __restrict__ w2, const float* __restrict__ b2,
    const float* __restrict__ w3, const float* __restrict__ b3,
    float* __restrict__ feat)
{
    __shared__ float xA[64 * 64];   // [ch][pix]
    __shared__ float xB[64 * 64];
    int tid  = threadIdx.x;
    int cg   = __builtin_amdgcn_readfirstlane(tid >> 6);
    int lane = tid & 63;
    int p = blockIdx.x * 64 + lane;
    int b = p >> 14;
    int q = p & 16383;
    int h = q >> 7;
    int w = q & 127;
    int c0 = cg * 16;

    float acc[16];
#pragma unroll
    for (int j = 0; j < 16; ++j) acc[j] = b0[c0 + j];

    const float* evb = ev + ((b * 64) * 64 + (h >> 1)) * 64 + (w >> 1);
    for (int i = 0; i < 64; ++i) {
        float v = evb[i * 4096];
        const float* wr = w0 + i * 64 + c0;
#pragma unroll
        for (int j = 0; j < 16; ++j) acc[j] = fmaf(v, wr[j], acc[j]);
    }
    const float* imb = im + ((b * 64) * 128 + h) * 128 + w;
    for (int i = 0; i < 64; ++i) {
        float v = imb[i * 16384];
        const float* wr = w0 + (64 + i) * 64 + c0;
#pragma unroll
        for (int j = 0; j < 16; ++j) acc[j] = fmaf(v, wr[j], acc[j]);
    }
    {
        float rely = (h & 1) ? 0.5f : -0.5f;
        float relx = (w & 1) ? 0.5f : -0.5f;
        const float* wr = w0 + 128 * 64 + c0;
#pragma unroll
        for (int j = 0; j < 16; ++j) acc[j] = fmaf(rely, wr[j], acc[j]);
#pragma unroll
        for (int j = 0; j < 16; ++j) acc[j] = fmaf(relx, wr[64 + j], acc[j]);
#pragma unroll
        for (int j = 0; j < 16; ++j) acc[j] += wr[128 + j] + wr[192 + j];
    }
#pragma unroll
    for (int j = 0; j < 16; ++j) xA[(c0 + j) * 64 + lane] = fmaxf(acc[j], 0.0f);
    __syncthreads();

#pragma unroll
    for (int j = 0; j < 16; ++j) acc[j] = b1[c0 + j];
    for (int i = 0; i < 64; ++i) {
        float v = xA[i * 64 + lane];
        const float* wr = w1 + i * 64 + c0;
#pragma unroll
        for (int j = 0; j < 16; ++j) acc[j] = fmaf(v, wr[j], acc[j]);
    }
#pragma unroll
    for (int j = 0; j < 16; ++j) xB[(c0 + j) * 64 + lane] = fmaxf(acc[j], 0.0f);
    __syncthreads();

#pragma unroll
    for (int j = 0; j < 16; ++j) acc[j] = b2[c0 + j];
    for (int i = 0; i < 64; ++i) {
        float v = xB[i * 64 + lane];
        const float* wr = w2 + i * 64 + c0;
#pragma unroll
        for (int j = 0; j < 16; ++j) acc[j] = fmaf(v, wr[j], acc[j]);
    }
#pragma unroll
    for (int j = 0; j < 16; ++j) xA[(c0 + j) * 64 + lane] = fmaxf(acc[j], 0.0f);
    __syncthreads();

#pragma unroll
    for (int j = 0; j < 16; ++j) acc[j] = b3[c0 + j];
    for (int i = 0; i < 64; ++i) {
        float v = xA[i * 64 + lane];
        const float* wr = w3 + i * 64 + c0;
#pragma unroll
        for (int j = 0; j < 16; ++j) acc[j] = fmaf(v, wr[j], acc[j]);
    }
    float* fb = feat + (b * 64 + c0) * 16384 + q;
#pragma unroll
    for (int j = 0; j < 16; ++j) fb[j * 16384] = acc[j];
}

// ---------------------------------------------------------------------------
// Kernel 2: 3x3 offset conv -> raw 27-ch oo.
// Block = 64 px x 4 waves; wave wv gathers windows for ic [16wv,16wv+16) only
// (4x less VMEM than o-split), partial acc[27], LDS cross-wave reduce.
// ---------------------------------------------------------------------------
__global__ __launch_bounds__(256) void off_kernel(
    const float* __restrict__ feat, const float* __restrict__ offT,
    const float* __restrict__ off_b,
    float* __restrict__ oo)
{
    __shared__ float po[4 * 27 * 64];   // [wave][o][px]
    int tid  = threadIdx.x;
    int wv   = __builtin_amdgcn_readfirstlane(tid >> 6);
    int lane = tid & 63;
    int p = blockIdx.x * 64 + lane;
    int b = p >> 14;
    int q = p & 16383;
    int h = q >> 7;
    int w = q & 127;
    int c0 = wv * 16;

    float acc[27];
#pragma unroll
    for (int o = 0; o < 27; ++o) acc[o] = 0.0f;

    const float* fb = feat + (b * 64 + c0) * 16384;
    for (int i = 0; i < 16; ++i) {
        const float* f = fb + i * 16384;
        float v[9];
#pragma unroll
        for (int ky = 0; ky < 3; ++ky)
#pragma unroll
            for (int kx = 0; kx < 3; ++kx) {
                int y = h + ky - 1, x = w + kx - 1;
                bool ok = (y >= 0) && (y < 128) && (x >= 0) && (x < 128);
                v[ky * 3 + kx] = ok ? f[y * 128 + x] : 0.0f;
            }
#pragma unroll
        for (int kk = 0; kk < 9; ++kk) {
            const float* wr = offT + ((c0 + i) * 9 + kk) * 28;
#pragma unroll
            for (int o = 0; o < 27; ++o) acc[o] = fmaf(v[kk], wr[o], acc[o]);
        }
    }

#pragma unroll
    for (int o = 0; o < 27; ++o) po[(wv * 27 + o) * 64 + lane] = acc[o];
    __syncthreads();

    // cross-wave reduce: wave wv sums outputs o = wv + 4j
#pragma unroll
    for (int j = 0; j < 7; ++j) {
        int o = wv + 4 * j;
        if (o < 27) {
            float s = off_b[o]
                    + po[o * 64 + lane] + po[(27 + o) * 64 + lane]
                    + po[(54 + o) * 64 + lane] + po[(81 + o) * 64 + lane];
            oo[((b * 27 + o) << 14) + q] = s;
        }
    }
}

// ---------------------------------------------------------------------------
// Kernel 3: transform + deformable sampling + einsum + bias.
// Block = 64 px x 4 waves. Per k: wave wv gathers bilinear samples for
// ic [16wv,16wv+16) -> LDS s[ic][px] (no redundancy); barrier; every wave
// FMAs all 64 ic into its o-slice [16wv,16wv+16) with wave-uniform weights.
// ---------------------------------------------------------------------------
__global__ __launch_bounds__(256) void dcn_kernel(
    const float* __restrict__ feat,
    const float* __restrict__ oo,
    const float* __restrict__ dcnT, const float* __restrict__ dcn_b,
    float* __restrict__ out)
{
    __shared__ float sbuf[64 * 64];   // [ic][px]
    int tid  = threadIdx.x;
    int wv   = __builtin_amdgcn_readfirstlane(tid >> 6);
    int lane = tid & 63;
    int p = blockIdx.x * 64 + lane;
    int b = p >> 14;
    int q = p & 16383;
    int h = q >> 7;
    int w = q & 127;
    int c0 = wv * 16;

    float acc[16];
#pragma unroll
    for (int j = 0; j < 16; ++j) acc[j] = dcn_b[c0 + j];

    const float* fb  = feat + (b * 64 + c0) * 16384;   // this wave's planes
    const float* oob = oo + ((b * 27) << 14) + q;

    for (int k = 0; k < 9; ++k) {
        float oy = oob[(2 * k) << 14];
        float ox = oob[(2 * k + 1) << 14];
        float ml = 1.0f / (1.0f + expf(-oob[(18 + k) << 14]));
        float py = (float)(h + k / 3 - 1) + oy;
        float px = (float)(w + k % 3 - 1) + ox;

        float y0f = floorf(py), x0f = floorf(px);
        float ly = py - y0f, lx = px - x0f;
        int y0 = (int)y0f, x0 = (int)x0f;

        bool vy0 = (y0f >= 0.0f)        && (y0f <= 127.0f);
        bool vy1 = (y0f + 1.0f >= 0.0f) && (y0f + 1.0f <= 127.0f);
        bool vx0 = (x0f >= 0.0f)        && (x0f <= 127.0f);
        bool vx1 = (x0f + 1.0f >= 0.0f) && (x0f + 1.0f <= 127.0f);

        int yc0 = min(max(y0, 0), 127),     yc1 = min(max(y0 + 1, 0), 127);
        int xc0 = min(max(x0, 0), 127),     xc1 = min(max(x0 + 1, 0), 127);

        float w00 = (1.0f - ly) * (1.0f - lx) * ml * ((vy0 && vx0) ? 1.0f : 0.0f);
        float w01 = (1.0f - ly) * lx          * ml * ((vy0 && vx1) ? 1.0f : 0.0f);
        float w10 = ly * (1.0f - lx)          * ml * ((vy1 && vx0) ? 1.0f : 0.0f);
        float w11 = ly * lx                   * ml * ((vy1 && vx1) ? 1.0f : 0.0f);

        int i00 = yc0 * 128 + xc0, i01 = yc0 * 128 + xc1;
        int i10 = yc1 * 128 + xc0, i11 = yc1 * 128 + xc1;

        // gather phase: this wave's 16 ic planes only
#pragma unroll 8
        for (int i = 0; i < 16; ++i) {
            const float* f = fb + i * 16384;
            float s = w00 * f[i00] + w01 * f[i01] + w10 * f[i10] + w11 * f[i11];
            sbuf[(c0 + i) * 64 + lane] = s;
        }
        __syncthreads();

        // FMA phase: all 64 ic into this wave's 16 outputs
        const float* wk = dcnT + (k * 64) * 64 + c0;
#pragma unroll 4
        for (int ic = 0; ic < 64; ++ic) {
            float s = sbuf[ic * 64 + lane];
            const float* wr = wk + ic * 64;
#pragma unroll
            for (int j = 0; j < 16; ++j) acc[j] = fmaf(s, wr[j], acc[j]);
        }
        __syncthreads();
    }

    float* ob = out + (b * 64 + c0) * 16384 + q;
#pragma unroll
    for (int j = 0; j < 16; ++j) ob[j * 16384] = acc[j];
}

// ---------------------------------------------------------------------------
extern "C" void kernel_launch(void* const* d_in, const int* in_sizes, int n_in,
                              void* d_out, int out_size, void* d_ws, size_t ws_size,
                              hipStream_t stream)
{
    const float* ev    = (const float*)d_in[0];
    const float* im    = (const float*)d_in[1];
    const float* w0    = (const float*)d_in[2];
    const float* b0    = (const float*)d_in[3];
    const float* w1    = (const float*)d_in[4];
    const float* b1    = (const float*)d_in[5];
    const float* w2    = (const float*)d_in[6];
    const float* b2    = (const float*)d_in[7];
    const float* w3    = (const float*)d_in[8];
    const float* b3    = (const float*)d_in[9];
    const float* off_w = (const float*)d_in[10];
    const float* off_b = (const float*)d_in[11];
    const float* dcn_w = (const float*)d_in[12];
    const float* dcn_b = (const float*)d_in[13];
    float* out = (float*)d_out;

    char* ws = (char*)d_ws;
    float* feat  = (float*)(ws);                       // 16,777,216 B
    float* oo    = (float*)(ws + 16777216);            //  7,077,888 B
    float* offT  = (float*)(ws + 23855104);            //     64,512 B
    float* dcnT  = (float*)(ws + 23920640);            //    147,456 B

    prep_kernel<<<144, 256, 0, stream>>>(off_w, dcn_w, offT, dcnT);
    mlp_kernel<<<NPIX / 64, 256, 0, stream>>>(ev, im, w0, b0, w1, b1, w2, b2,
                                              w3, b3, feat);
    off_kernel<<<NPIX / 64, 256, 0, stream>>>(feat, offT, off_b, oo);
    dcn_kernel<<<NPIX / 64, 256, 0, stream>>>(feat, oo, dcnT, dcn_b, out);
}

// Round 4
// 185.959 us; speedup vs baseline: 2.2936x; 1.0507x over previous
//
#include <hip/hip_runtime.h>
#include <math.h>

// Problem constants
#define CCH 64
#define HH  128
#define WW  128
#define NB  4
#define NPIX (NB*HH*WW)   // 65536
#define NWG  (NPIX/64)    // 1024 blocks for the pixel kernels

// XCD-aware block swizzle (T1): hardware assigns consecutive blockIdx
// round-robin across 8 XCDs; remap so each XCD gets a CONTIGUOUS chunk of
// logical block space (64 contiguous image rows -> 2MB feat slice, fits the
// 4MB per-XCD L2). nwg % 8 == 0 -> bijective.
__device__ __forceinline__ int swz_block(int bid) {
    return (bid & 7) * (NWG >> 3) + (bid >> 3);
}

// ---------------------------------------------------------------------------
// Prep: transpose conv weights for wave-uniform contiguous rows.
//   offT[(ic*9+kk)*28 + o]  = off_w[o*576 + ic*9 + kk]   (o<27, pad->0)
//   dcnT[(k*64+ic)*64 + o]  = dcn_w[o*576 + ic*9 + k]
// ---------------------------------------------------------------------------
__global__ __launch_bounds__(256) void prep_kernel(
    const float* __restrict__ off_w, const float* __restrict__ dcn_w,
    float* __restrict__ offT, float* __restrict__ dcnT)
{
    int idx = blockIdx.x * 256 + threadIdx.x;
    if (idx < 576 * 28) {
        int rc = idx / 28;       // ic*9+kk
        int o  = idx % 28;
        offT[rc * 28 + o] = (o < 27) ? off_w[o * 576 + rc] : 0.0f;
    }
    if (idx < 36864) {
        int o    = idx & 63;
        int rest = idx >> 6;
        int ic   = rest & 63;
        int k    = rest >> 6;
        dcnT[(k * 64 + ic) * 64 + o] = dcn_w[o * 576 + ic * 9 + k];
    }
}

// ---------------------------------------------------------------------------
// Kernel 1: fused 4-layer MLP -> feat (NCHW).
// Block = 64 pixels x 4 waves; wave cg computes channels [16cg,16cg+16).
// ---------------------------------------------------------------------------
__global__ __launch_bounds__(256) void mlp_kernel(
    const float* __restrict__ ev, const float* __restrict__ im,
    const float* __restrict__ w0, const float* __restrict__ b0,
    const float* __restrict__ w1, const float* __restrict__ b1,
    const float* __restrict__ w2, const float* __restrict__ b2,
    const float* __restrict__ w3, const float* __restrict__ b3,
    float* __restrict__ feat)
{
    __shared__ float xA[64 * 64];   // [ch][pix]
    __shared__ float xB[64 * 64];
    int tid  = threadIdx.x;
    int cg   = __builtin_amdgcn_readfirstlane(tid >> 6);
    int lane = tid & 63;
    int p = swz_block(blockIdx.x) * 64 + lane;
    int b = p >> 14;
    int q = p & 16383;
    int h = q >> 7;
    int w = q & 127;
    int c0 = cg * 16;

    float acc[16];
#pragma unroll
    for (int j = 0; j < 16; ++j) acc[j] = b0[c0 + j];

    const float* evb = ev + ((b * 64) * 64 + (h >> 1)) * 64 + (w >> 1);
    for (int i = 0; i < 64; ++i) {
        float v = evb[i * 4096];
        const float* wr = w0 + i * 64 + c0;
#pragma unroll
        for (int j = 0; j < 16; ++j) acc[j] = fmaf(v, wr[j], acc[j]);
    }
    const float* imb = im + ((b * 64) * 128 + h) * 128 + w;
    for (int i = 0; i < 64; ++i) {
        float v = imb[i * 16384];
        const float* wr = w0 + (64 + i) * 64 + c0;
#pragma unroll
        for (int j = 0; j < 16; ++j) acc[j] = fmaf(v, wr[j], acc[j]);
    }
    {
        float rely = (h & 1) ? 0.5f : -0.5f;
        float relx = (w & 1) ? 0.5f : -0.5f;
        const float* wr = w0 + 128 * 64 + c0;
#pragma unroll
        for (int j = 0; j < 16; ++j) acc[j] = fmaf(rely, wr[j], acc[j]);
#pragma unroll
        for (int j = 0; j < 16; ++j) acc[j] = fmaf(relx, wr[64 + j], acc[j]);
#pragma unroll
        for (int j = 0; j < 16; ++j) acc[j] += wr[128 + j] + wr[192 + j];
    }
#pragma unroll
    for (int j = 0; j < 16; ++j) xA[(c0 + j) * 64 + lane] = fmaxf(acc[j], 0.0f);
    __syncthreads();

#pragma unroll
    for (int j = 0; j < 16; ++j) acc[j] = b1[c0 + j];
    for (int i = 0; i < 64; ++i) {
        float v = xA[i * 64 + lane];
        const float* wr = w1 + i * 64 + c0;
#pragma unroll
        for (int j = 0; j < 16; ++j) acc[j] = fmaf(v, wr[j], acc[j]);
    }
#pragma unroll
    for (int j = 0; j < 16; ++j) xB[(c0 + j) * 64 + lane] = fmaxf(acc[j], 0.0f);
    __syncthreads();

#pragma unroll
    for (int j = 0; j < 16; ++j) acc[j] = b2[c0 + j];
    for (int i = 0; i < 64; ++i) {
        float v = xB[i * 64 + lane];
        const float* wr = w2 + i * 64 + c0;
#pragma unroll
        for (int j = 0; j < 16; ++j) acc[j] = fmaf(v, wr[j], acc[j]);
    }
#pragma unroll
    for (int j = 0; j < 16; ++j) xA[(c0 + j) * 64 + lane] = fmaxf(acc[j], 0.0f);
    __syncthreads();

#pragma unroll
    for (int j = 0; j < 16; ++j) acc[j] = b3[c0 + j];
    for (int i = 0; i < 64; ++i) {
        float v = xA[i * 64 + lane];
        const float* wr = w3 + i * 64 + c0;
#pragma unroll
        for (int j = 0; j < 16; ++j) acc[j] = fmaf(v, wr[j], acc[j]);
    }
    float* fb = feat + (b * 64 + c0) * 16384 + q;
#pragma unroll
    for (int j = 0; j < 16; ++j) fb[j * 16384] = acc[j];
}

// ---------------------------------------------------------------------------
// Kernel 2: 3x3 offset conv -> raw 27-ch oo.
// Block = 64 px x 4 waves; wave wv gathers windows for ic [16wv,16wv+16),
// partial acc[27], LDS cross-wave reduce.
// ---------------------------------------------------------------------------
__global__ __launch_bounds__(256) void off_kernel(
    const float* __restrict__ feat, const float* __restrict__ offT,
    const float* __restrict__ off_b,
    float* __restrict__ oo)
{
    __shared__ float po[4 * 27 * 64];   // [wave][o][px]
    int tid  = threadIdx.x;
    int wv   = __builtin_amdgcn_readfirstlane(tid >> 6);
    int lane = tid & 63;
    int p = swz_block(blockIdx.x) * 64 + lane;
    int b = p >> 14;
    int q = p & 16383;
    int h = q >> 7;
    int w = q & 127;
    int c0 = wv * 16;

    float acc[27];
#pragma unroll
    for (int o = 0; o < 27; ++o) acc[o] = 0.0f;

    const float* fb = feat + (b * 64 + c0) * 16384;
    for (int i = 0; i < 16; ++i) {
        const float* f = fb + i * 16384;
        float v[9];
#pragma unroll
        for (int ky = 0; ky < 3; ++ky)
#pragma unroll
            for (int kx = 0; kx < 3; ++kx) {
                int y = h + ky - 1, x = w + kx - 1;
                bool ok = (y >= 0) && (y < 128) && (x >= 0) && (x < 128);
                v[ky * 3 + kx] = ok ? f[y * 128 + x] : 0.0f;
            }
#pragma unroll
        for (int kk = 0; kk < 9; ++kk) {
            const float* wr = offT + ((c0 + i) * 9 + kk) * 28;
#pragma unroll
            for (int o = 0; o < 27; ++o) acc[o] = fmaf(v[kk], wr[o], acc[o]);
        }
    }

#pragma unroll
    for (int o = 0; o < 27; ++o) po[(wv * 27 + o) * 64 + lane] = acc[o];
    __syncthreads();

    // cross-wave reduce: wave wv sums outputs o = wv + 4j
#pragma unroll
    for (int j = 0; j < 7; ++j) {
        int o = wv + 4 * j;
        if (o < 27) {
            float s = off_b[o]
                    + po[o * 64 + lane] + po[(27 + o) * 64 + lane]
                    + po[(54 + o) * 64 + lane] + po[(81 + o) * 64 + lane];
            oo[((b * 27 + o) << 14) + q] = s;
        }
    }
}

// ---------------------------------------------------------------------------
// Kernel 3: transform + deformable sampling + einsum + bias.
// Block = 64 px x 4 waves. Per k: wave wv gathers bilinear samples for
// ic [16wv,16wv+16) -> LDS s[ic][px]; barrier; every wave FMAs all 64 ic
// into its o-slice with wave-uniform weights.
// ---------------------------------------------------------------------------
__global__ __launch_bounds__(256) void dcn_kernel(
    const float* __restrict__ feat,
    const float* __restrict__ oo,
    const float* __restrict__ dcnT, const float* __restrict__ dcn_b,
    float* __restrict__ out)
{
    __shared__ float sbuf[64 * 64];   // [ic][px]
    int tid  = threadIdx.x;
    int wv   = __builtin_amdgcn_readfirstlane(tid >> 6);
    int lane = tid & 63;
    int p = swz_block(blockIdx.x) * 64 + lane;
    int b = p >> 14;
    int q = p & 16383;
    int h = q >> 7;
    int w = q & 127;
    int c0 = wv * 16;

    float acc[16];
#pragma unroll
    for (int j = 0; j < 16; ++j) acc[j] = dcn_b[c0 + j];

    const float* fb  = feat + (b * 64 + c0) * 16384;   // this wave's planes
    const float* oob = oo + ((b * 27) << 14) + q;

    for (int k = 0; k < 9; ++k) {
        float oy = oob[(2 * k) << 14];
        float ox = oob[(2 * k + 1) << 14];
        float ml = 1.0f / (1.0f + expf(-oob[(18 + k) << 14]));
        float py = (float)(h + k / 3 - 1) + oy;
        float px = (float)(w + k % 3 - 1) + ox;

        float y0f = floorf(py), x0f = floorf(px);
        float ly = py - y0f, lx = px - x0f;
        int y0 = (int)y0f, x0 = (int)x0f;

        bool vy0 = (y0f >= 0.0f)        && (y0f <= 127.0f);
        bool vy1 = (y0f + 1.0f >= 0.0f) && (y0f + 1.0f <= 127.0f);
        bool vx0 = (x0f >= 0.0f)        && (x0f <= 127.0f);
        bool vx1 = (x0f + 1.0f >= 0.0f) && (x0f + 1.0f <= 127.0f);

        int yc0 = min(max(y0, 0), 127),     yc1 = min(max(y0 + 1, 0), 127);
        int xc0 = min(max(x0, 0), 127),     xc1 = min(max(x0 + 1, 0), 127);

        float w00 = (1.0f - ly) * (1.0f - lx) * ml * ((vy0 && vx0) ? 1.0f : 0.0f);
        float w01 = (1.0f - ly) * lx          * ml * ((vy0 && vx1) ? 1.0f : 0.0f);
        float w10 = ly * (1.0f - lx)          * ml * ((vy1 && vx0) ? 1.0f : 0.0f);
        float w11 = ly * lx                   * ml * ((vy1 && vx1) ? 1.0f : 0.0f);

        int i00 = yc0 * 128 + xc0, i01 = yc0 * 128 + xc1;
        int i10 = yc1 * 128 + xc0, i11 = yc1 * 128 + xc1;

        // gather phase: this wave's 16 ic planes only
#pragma unroll 8
        for (int i = 0; i < 16; ++i) {
            const float* f = fb + i * 16384;
            float s = w00 * f[i00] + w01 * f[i01] + w10 * f[i10] + w11 * f[i11];
            sbuf[(c0 + i) * 64 + lane] = s;
        }
        __syncthreads();

        // FMA phase: all 64 ic into this wave's 16 outputs
        const float* wk = dcnT + (k * 64) * 64 + c0;
#pragma unroll 4
        for (int ic = 0; ic < 64; ++ic) {
            float s = sbuf[ic * 64 + lane];
            const float* wr = wk + ic * 64;
#pragma unroll
            for (int j = 0; j < 16; ++j) acc[j] = fmaf(s, wr[j], acc[j]);
        }
        __syncthreads();
    }

    float* ob = out + (b * 64 + c0) * 16384 + q;
#pragma unroll
    for (int j = 0; j < 16; ++j) ob[j * 16384] = acc[j];
}

// ---------------------------------------------------------------------------
extern "C" void kernel_launch(void* const* d_in, const int* in_sizes, int n_in,
                              void* d_out, int out_size, void* d_ws, size_t ws_size,
                              hipStream_t stream)
{
    const float* ev    = (const float*)d_in[0];
    const float* im    = (const float*)d_in[1];
    const float* w0    = (const float*)d_in[2];
    const float* b0    = (const float*)d_in[3];
    const float* w1    = (const float*)d_in[4];
    const float* b1    = (const float*)d_in[5];
    const float* w2    = (const float*)d_in[6];
    const float* b2    = (const float*)d_in[7];
    const float* w3    = (const float*)d_in[8];
    const float* b3    = (const float*)d_in[9];
    const float* off_w = (const float*)d_in[10];
    const float* off_b = (const float*)d_in[11];
    const float* dcn_w = (const float*)d_in[12];
    const float* dcn_b = (const float*)d_in[13];
    float* out = (float*)d_out;

    char* ws = (char*)d_ws;
    float* feat  = (float*)(ws);                       // 16,777,216 B
    float* oo    = (float*)(ws + 16777216);            //  7,077,888 B
    float* offT  = (float*)(ws + 23855104);            //     64,512 B
    float* dcnT  = (float*)(ws + 23920640);            //    147,456 B

    prep_kernel<<<144, 256, 0, stream>>>(off_w, dcn_w, offT, dcnT);
    mlp_kernel<<<NWG, 256, 0, stream>>>(ev, im, w0, b0, w1, b1, w2, b2,
                                        w3, b3, feat);
    off_kernel<<<NWG, 256, 0, stream>>>(feat, offT, off_b, oo);
    dcn_kernel<<<NWG, 256, 0, stream>>>(feat, oo, dcnT, dcn_b, out);
}

// Round 5
// 182.067 us; speedup vs baseline: 2.3426x; 1.0214x over previous
//
#include <hip/hip_runtime.h>
#include <math.h>

// Problem constants
#define CCH 64
#define HH  128
#define WW  128
#define NB  4
#define NPIX (NB*HH*WW)   // 65536
#define NWG  (NPIX/64)    // 1024 blocks for the pixel kernels

// XCD-aware block swizzle (T1): each XCD gets a contiguous 64-row slice
// (2MB of feat -> fits 4MB per-XCD L2). nwg % 8 == 0 -> bijective.
__device__ __forceinline__ int swz_block(int bid) {
    return (bid & 7) * (NWG >> 3) + (bid >> 3);
}

// ---------------------------------------------------------------------------
// Prep: transpose conv weights for wave-uniform contiguous rows.
// ---------------------------------------------------------------------------
__global__ __launch_bounds__(256) void prep_kernel(
    const float* __restrict__ off_w, const float* __restrict__ dcn_w,
    float* __restrict__ offT, float* __restrict__ dcnT)
{
    int idx = blockIdx.x * 256 + threadIdx.x;
    if (idx < 576 * 28) {
        int rc = idx / 28;       // ic*9+kk
        int o  = idx % 28;
        offT[rc * 28 + o] = (o < 27) ? off_w[o * 576 + rc] : 0.0f;
    }
    if (idx < 36864) {
        int o    = idx & 63;
        int rest = idx >> 6;
        int ic   = rest & 63;
        int k    = rest >> 6;
        dcnT[(k * 64 + ic) * 64 + o] = dcn_w[o * 576 + ic * 9 + k];
    }
}

// ---------------------------------------------------------------------------
// Kernel 1: fused 4-layer MLP -> feat (NCHW).
// ---------------------------------------------------------------------------
__global__ __launch_bounds__(256) void mlp_kernel(
    const float* __restrict__ ev, const float* __restrict__ im,
    const float* __restrict__ w0, const float* __restrict__ b0,
    const float* __restrict__ w1, const float* __restrict__ b1,
    const float* __restrict__ w2, const float* __restrict__ b2,
    const float* __restrict__ w3, const float* __restrict__ b3,
    float* __restrict__ feat)
{
    __shared__ float xA[64 * 64];   // [ch][pix]
    __shared__ float xB[64 * 64];
    int tid  = threadIdx.x;
    int cg   = __builtin_amdgcn_readfirstlane(tid >> 6);
    int lane = tid & 63;
    int p = swz_block(blockIdx.x) * 64 + lane;
    int b = p >> 14;
    int q = p & 16383;
    int h = q >> 7;
    int w = q & 127;
    int c0 = cg * 16;

    float acc[16];
#pragma unroll
    for (int j = 0; j < 16; ++j) acc[j] = b0[c0 + j];

    const float* evb = ev + ((b * 64) * 64 + (h >> 1)) * 64 + (w >> 1);
    for (int i = 0; i < 64; ++i) {
        float v = evb[i * 4096];
        const float* wr = w0 + i * 64 + c0;
#pragma unroll
        for (int j = 0; j < 16; ++j) acc[j] = fmaf(v, wr[j], acc[j]);
    }
    const float* imb = im + ((b * 64) * 128 + h) * 128 + w;
    for (int i = 0; i < 64; ++i) {
        float v = imb[i * 16384];
        const float* wr = w0 + (64 + i) * 64 + c0;
#pragma unroll
        for (int j = 0; j < 16; ++j) acc[j] = fmaf(v, wr[j], acc[j]);
    }
    {
        float rely = (h & 1) ? 0.5f : -0.5f;
        float relx = (w & 1) ? 0.5f : -0.5f;
        const float* wr = w0 + 128 * 64 + c0;
#pragma unroll
        for (int j = 0; j < 16; ++j) acc[j] = fmaf(rely, wr[j], acc[j]);
#pragma unroll
        for (int j = 0; j < 16; ++j) acc[j] = fmaf(relx, wr[64 + j], acc[j]);
#pragma unroll
        for (int j = 0; j < 16; ++j) acc[j] += wr[128 + j] + wr[192 + j];
    }
#pragma unroll
    for (int j = 0; j < 16; ++j) xA[(c0 + j) * 64 + lane] = fmaxf(acc[j], 0.0f);
    __syncthreads();

#pragma unroll
    for (int j = 0; j < 16; ++j) acc[j] = b1[c0 + j];
    for (int i = 0; i < 64; ++i) {
        float v = xA[i * 64 + lane];
        const float* wr = w1 + i * 64 + c0;
#pragma unroll
        for (int j = 0; j < 16; ++j) acc[j] = fmaf(v, wr[j], acc[j]);
    }
#pragma unroll
    for (int j = 0; j < 16; ++j) xB[(c0 + j) * 64 + lane] = fmaxf(acc[j], 0.0f);
    __syncthreads();

#pragma unroll
    for (int j = 0; j < 16; ++j) acc[j] = b2[c0 + j];
    for (int i = 0; i < 64; ++i) {
        float v = xB[i * 64 + lane];
        const float* wr = w2 + i * 64 + c0;
#pragma unroll
        for (int j = 0; j < 16; ++j) acc[j] = fmaf(v, wr[j], acc[j]);
    }
#pragma unroll
    for (int j = 0; j < 16; ++j) xA[(c0 + j) * 64 + lane] = fmaxf(acc[j], 0.0f);
    __syncthreads();

#pragma unroll
    for (int j = 0; j < 16; ++j) acc[j] = b3[c0 + j];
    for (int i = 0; i < 64; ++i) {
        float v = xA[i * 64 + lane];
        const float* wr = w3 + i * 64 + c0;
#pragma unroll
        for (int j = 0; j < 16; ++j) acc[j] = fmaf(v, wr[j], acc[j]);
    }
    float* fb = feat + (b * 64 + c0) * 16384 + q;
#pragma unroll
    for (int j = 0; j < 16; ++j) fb[j * 16384] = acc[j];
}

// ---------------------------------------------------------------------------
// Kernel 2: 3x3 offset conv -> raw 27-ch oo.
// ---------------------------------------------------------------------------
__global__ __launch_bounds__(256) void off_kernel(
    const float* __restrict__ feat, const float* __restrict__ offT,
    const float* __restrict__ off_b,
    float* __restrict__ oo)
{
    __shared__ float po[4 * 27 * 64];   // [wave][o][px]
    int tid  = threadIdx.x;
    int wv   = __builtin_amdgcn_readfirstlane(tid >> 6);
    int lane = tid & 63;
    int p = swz_block(blockIdx.x) * 64 + lane;
    int b = p >> 14;
    int q = p & 16383;
    int h = q >> 7;
    int w = q & 127;
    int c0 = wv * 16;

    float acc[27];
#pragma unroll
    for (int o = 0; o < 27; ++o) acc[o] = 0.0f;

    const float* fb = feat + (b * 64 + c0) * 16384;
    for (int i = 0; i < 16; ++i) {
        const float* f = fb + i * 16384;
        float v[9];
#pragma unroll
        for (int ky = 0; ky < 3; ++ky)
#pragma unroll
            for (int kx = 0; kx < 3; ++kx) {
                int y = h + ky - 1, x = w + kx - 1;
                bool ok = (y >= 0) && (y < 128) && (x >= 0) && (x < 128);
                v[ky * 3 + kx] = ok ? f[y * 128 + x] : 0.0f;
            }
#pragma unroll
        for (int kk = 0; kk < 9; ++kk) {
            const float* wr = offT + ((c0 + i) * 9 + kk) * 28;
#pragma unroll
            for (int o = 0; o < 27; ++o) acc[o] = fmaf(v[kk], wr[o], acc[o]);
        }
    }

#pragma unroll
    for (int o = 0; o < 27; ++o) po[(wv * 27 + o) * 64 + lane] = acc[o];
    __syncthreads();

#pragma unroll
    for (int j = 0; j < 7; ++j) {
        int o = wv + 4 * j;
        if (o < 27) {
            float s = off_b[o]
                    + po[o * 64 + lane] + po[(27 + o) * 64 + lane]
                    + po[(54 + o) * 64 + lane] + po[(81 + o) * 64 + lane];
            oo[((b * 27 + o) << 14) + q] = s;
        }
    }
}

// ---------------------------------------------------------------------------
// Kernel 3: transform + deformable sampling + einsum + bias.
// Double-buffered pipeline: per k, issue k+1 gather loads (8+8 ic) around
// the k FMA half-phases; single barrier per k.
// ---------------------------------------------------------------------------
__device__ __forceinline__ void dcn_transform(
    const float* oob, int k, int h, int w,
    float& W00, float& W01, float& W10, float& W11,
    int& i00, int& i01, int& i10, int& i11)
{
    float oy = oob[(2 * k) << 14];
    float ox = oob[(2 * k + 1) << 14];
    float ml = 1.0f / (1.0f + expf(-oob[(18 + k) << 14]));
    float py = (float)(h + k / 3 - 1) + oy;
    float px = (float)(w + k % 3 - 1) + ox;

    float y0f = floorf(py), x0f = floorf(px);
    float ly = py - y0f, lx = px - x0f;
    int y0 = (int)y0f, x0 = (int)x0f;

    bool vy0 = (y0f >= 0.0f)        && (y0f <= 127.0f);
    bool vy1 = (y0f + 1.0f >= 0.0f) && (y0f + 1.0f <= 127.0f);
    bool vx0 = (x0f >= 0.0f)        && (x0f <= 127.0f);
    bool vx1 = (x0f + 1.0f >= 0.0f) && (x0f + 1.0f <= 127.0f);

    int yc0 = min(max(y0, 0), 127),     yc1 = min(max(y0 + 1, 0), 127);
    int xc0 = min(max(x0, 0), 127),     xc1 = min(max(x0 + 1, 0), 127);

    W00 = (1.0f - ly) * (1.0f - lx) * ml * ((vy0 && vx0) ? 1.0f : 0.0f);
    W01 = (1.0f - ly) * lx          * ml * ((vy0 && vx1) ? 1.0f : 0.0f);
    W10 = ly * (1.0f - lx)          * ml * ((vy1 && vx0) ? 1.0f : 0.0f);
    W11 = ly * lx                   * ml * ((vy1 && vx1) ? 1.0f : 0.0f);

    i00 = yc0 * 128 + xc0; i01 = yc0 * 128 + xc1;
    i10 = yc1 * 128 + xc0; i11 = yc1 * 128 + xc1;
}

__global__ __launch_bounds__(256) void dcn_kernel(
    const float* __restrict__ feat,
    const float* __restrict__ oo,
    const float* __restrict__ dcnT, const float* __restrict__ dcn_b,
    float* __restrict__ out)
{
    __shared__ float sA[64 * 64];   // [ic][px]
    __shared__ float sB[64 * 64];
    int tid  = threadIdx.x;
    int wv   = __builtin_amdgcn_readfirstlane(tid >> 6);
    int lane = tid & 63;
    int p = swz_block(blockIdx.x) * 64 + lane;
    int b = p >> 14;
    int q = p & 16383;
    int h = q >> 7;
    int w = q & 127;
    int c0 = wv * 16;

    float acc[16];
#pragma unroll
    for (int j = 0; j < 16; ++j) acc[j] = dcn_b[c0 + j];

    const float* fb  = feat + (b * 64 + c0) * 16384;   // this wave's planes
    const float* oob = oo + ((b * 27) << 14) + q;

    // ---- prologue: gather k=0 into sA ----
    {
        float W00, W01, W10, W11; int i00, i01, i10, i11;
        dcn_transform(oob, 0, h, w, W00, W01, W10, W11, i00, i01, i10, i11);
#pragma unroll 8
        for (int i = 0; i < 16; ++i) {
            const float* f = fb + i * 16384;
            float s = W00 * f[i00] + W01 * f[i01] + W10 * f[i10] + W11 * f[i11];
            sA[(c0 + i) * 64 + lane] = s;
        }
    }
    __syncthreads();

    float* cur = sA;
    float* nxt = sB;

    for (int k = 0; k < 9; ++k) {
        bool pre = (k < 8);
        float W00, W01, W10, W11; int i00, i01, i10, i11;
        float r00[8], r01[8], r10[8], r11[8];

        if (pre) {
            dcn_transform(oob, k + 1, h, w, W00, W01, W10, W11, i00, i01, i10, i11);
            // issue first 8 ic gather loads (hide under FMA half-phase 1)
#pragma unroll
            for (int i = 0; i < 8; ++i) {
                const float* f = fb + i * 16384;
                r00[i] = f[i00]; r01[i] = f[i01]; r10[i] = f[i10]; r11[i] = f[i11];
            }
        }

        const float* wk = dcnT + (k * 64) * 64 + c0;
        // FMA half-phase 1: ic 0..31
#pragma unroll 8
        for (int ic = 0; ic < 32; ++ic) {
            float s = cur[ic * 64 + lane];
            const float* wr = wk + ic * 64;
#pragma unroll
            for (int j = 0; j < 16; ++j) acc[j] = fmaf(s, wr[j], acc[j]);
        }

        if (pre) {
            // consume batch 1 -> LDS; issue second 8 ic loads
#pragma unroll
            for (int i = 0; i < 8; ++i)
                nxt[(c0 + i) * 64 + lane] =
                    W00 * r00[i] + W01 * r01[i] + W10 * r10[i] + W11 * r11[i];
#pragma unroll
            for (int i = 0; i < 8; ++i) {
                const float* f = fb + (8 + i) * 16384;
                r00[i] = f[i00]; r01[i] = f[i01]; r10[i] = f[i10]; r11[i] = f[i11];
            }
        }

        // FMA half-phase 2: ic 32..63
#pragma unroll 8
        for (int ic = 32; ic < 64; ++ic) {
            float s = cur[ic * 64 + lane];
            const float* wr = wk + ic * 64;
#pragma unroll
            for (int j = 0; j < 16; ++j) acc[j] = fmaf(s, wr[j], acc[j]);
        }

        if (pre) {
#pragma unroll
            for (int i = 0; i < 8; ++i)
                nxt[(c0 + 8 + i) * 64 + lane] =
                    W00 * r00[i] + W01 * r01[i] + W10 * r10[i] + W11 * r11[i];
        }

        __syncthreads();
        float* t = cur; cur = nxt; nxt = t;
    }

    float* ob = out + (b * 64 + c0) * 16384 + q;
#pragma unroll
    for (int j = 0; j < 16; ++j) ob[j * 16384] = acc[j];
}

// ---------------------------------------------------------------------------
extern "C" void kernel_launch(void* const* d_in, const int* in_sizes, int n_in,
                              void* d_out, int out_size, void* d_ws, size_t ws_size,
                              hipStream_t stream)
{
    const float* ev    = (const float*)d_in[0];
    const float* im    = (const float*)d_in[1];
    const float* w0    = (const float*)d_in[2];
    const float* b0    = (const float*)d_in[3];
    const float* w1    = (const float*)d_in[4];
    const float* b1    = (const float*)d_in[5];
    const float* w2    = (const float*)d_in[6];
    const float* b2    = (const float*)d_in[7];
    const float* w3    = (const float*)d_in[8];
    const float* b3    = (const float*)d_in[9];
    const float* off_w = (const float*)d_in[10];
    const float* off_b = (const float*)d_in[11];
    const float* dcn_w = (const float*)d_in[12];
    const float* dcn_b = (const float*)d_in[13];
    float* out = (float*)d_out;

    char* ws = (char*)d_ws;
    float* feat  = (float*)(ws);                       // 16,777,216 B
    float* oo    = (float*)(ws + 16777216);            //  7,077,888 B
    float* offT  = (float*)(ws + 23855104);            //     64,512 B
    float* dcnT  = (float*)(ws + 23920640);            //    147,456 B

    prep_kernel<<<144, 256, 0, stream>>>(off_w, dcn_w, offT, dcnT);
    mlp_kernel<<<NWG, 256, 0, stream>>>(ev, im, w0, b0, w1, b1, w2, b2,
                                        w3, b3, feat);
    off_kernel<<<NWG, 256, 0, stream>>>(feat, offT, off_b, oo);
    dcn_kernel<<<NWG, 256, 0, stream>>>(feat, oo, dcnT, dcn_b, out);
}